// Round 17
// baseline (288.981 us; speedup 1.0000x reference)
//
#include <hip/hip_runtime.h>
#include <hip/hip_bf16.h>
#include <math.h>

#define N_NODES 50000
#define N_EDGES 640000
#define IN_DIM 5
#define HID 128
#define NGRAPH 512
#define SCAN_NBLK ((N_NODES + 255) / 256)  // 196
#define GEMM_NBLK ((N_NODES + 63) / 64)    // 782
#define CNT_BLK ((N_EDGES + 255) / 256)    // 2500
#define PREP_BLK 128                        // 2 weight mats x 64

typedef unsigned short u16;
typedef __attribute__((ext_vector_type(8))) short bf16x8;
typedef __attribute__((ext_vector_type(8))) unsigned short u16x8;
typedef __attribute__((ext_vector_type(4))) float f32x4;
typedef __attribute__((ext_vector_type(8))) float f32x8;

__device__ __forceinline__ float bf2f(u16 u) {
  union { unsigned int i; float f; } v; v.i = ((unsigned int)u) << 16; return v.f;
}
__device__ __forceinline__ u16 f2bf(float f) {
  return __bfloat16_as_ushort(__float2bfloat16(f));
}

// ---------------- Fused setup: count_edges + W1 prep + wvecs + nrow ----------------
// wvecs[0:128) = Wrel2@Wlin, [128:256) = Wroot2@Wlin, [256] = b2.Wlin
__global__ __launch_bounds__(256) void setup_k(const int* __restrict__ dst,
                                               int* __restrict__ counts,
                                               const float* __restrict__ W1rel,
                                               const float* __restrict__ W1root,
                                               u16* __restrict__ T1rel, u16* __restrict__ T1root,
                                               const float* __restrict__ Wrel2,
                                               const float* __restrict__ Wroot2,
                                               const float* __restrict__ b2,
                                               const float* __restrict__ Wlin,
                                               float* __restrict__ wvecs,
                                               const int* __restrict__ batch,
                                               int* __restrict__ nrow) {
  int b = blockIdx.x;
  if (b < CNT_BLK) {
    int e = b * 256 + threadIdx.x;
    if (e < N_EDGES) atomicAdd(&counts[dst[e]], 1);
  } else if (b < CNT_BLK + PREP_BLK) {
    int bb = b - CNT_BLK;
    int which = bb >> 6;
    int idx = (bb & 63) * 256 + threadIdx.x;  // k*128 + n
    const float* W = which == 0 ? W1rel : W1root;
    u16* T = which == 0 ? T1rel : T1root;
    int k = idx >> 7, n = idx & 127;
    T[n * HID + k] = f2bf(W[idx]);
  } else if (b == CNT_BLK + PREP_BLK) {
    int t = threadIdx.x;
    if (t < 128) {
      float s = 0.f;
      for (int c = 0; c < HID; ++c) s = fmaf(Wrel2[t * HID + c], Wlin[c], s);
      wvecs[t] = s;
    } else {
      int k = t - 128;
      float s = 0.f;
      for (int c = 0; c < HID; ++c) s = fmaf(Wroot2[k * HID + c], Wlin[c], s);
      wvecs[128 + k] = s;
    }
    if (t == 0) {
      float s = 0.f;
      for (int c = 0; c < HID; ++c) s = fmaf(b2[c], Wlin[c], s);
      wvecs[256] = s;
    }
  } else {
    // nrow: graph node boundaries from sorted batch (handles empty graphs)
    int n = (b - CNT_BLK - PREP_BLK - 1) * 256 + threadIdx.x;
    if (n < N_NODES) {
      int bg = batch[n];
      int bp = (n == 0) ? -1 : batch[n - 1];
      for (int g = bp + 1; g <= bg; ++g) nrow[g] = n;
      if (n == N_NODES - 1) {
        for (int g = bg + 1; g <= NGRAPH; ++g) nrow[g] = N_NODES;
      }
    }
  }
}

// ---------------- Fused scan: per-block self-computed offset + local scan ----------
// (round-16: partial_k deleted; each block strides counts[0..256b) -> ~20MB L2 reads)
__global__ __launch_bounds__(256) void scan_fused_k(const int* __restrict__ counts,
                                                    int* __restrict__ row_ptr,
                                                    int* __restrict__ fill_off) {
  __shared__ int s[256];
  __shared__ int wred[4];
  int t = threadIdx.x;
  int b = blockIdx.x;
  int base = b * 256;
  int v = 0;
  for (int i = t; i < base; i += 256) v += counts[i];
#pragma unroll
  for (int off = 32; off; off >>= 1) v += __shfl_down(v, off, 64);
  if ((t & 63) == 0) wred[t >> 6] = v;
  __syncthreads();
  int boff = wred[0] + wred[1] + wred[2] + wred[3];
  int i = base + t;
  int c = (i < N_NODES) ? counts[i] : 0;
  s[t] = c;
  __syncthreads();
#pragma unroll
  for (int off = 1; off < 256; off <<= 1) {
    int u = (t >= off) ? s[t - off] : 0;
    __syncthreads();
    s[t] += u;
    __syncthreads();
  }
  int excl = s[t] - c + boff;
  if (i < N_NODES) {
    row_ptr[i] = excl;
    fill_off[i] = excl;
  }
  if (b == SCAN_NBLK - 1 && t == 255) row_ptr[N_NODES] = s[255] + boff;
}

__global__ void fill_edges_k(const int* __restrict__ src, const int* __restrict__ dst,
                             int* __restrict__ fill_off, int* __restrict__ esrc) {
  int e = blockIdx.x * blockDim.x + threadIdx.x;
  if (e < N_EDGES) {
    int d = dst[e];
    int pos = atomicAdd(&fill_off[d], 1);
    esrc[pos] = src[e];
  }
}

// ---------------- Fused layer-0 + layer-1 MFMA GEMM ----------------
// The block only needs HA rows r0..r0+63, so compute layer 0 (input-space
// gather + 5->128 projection) directly into the As LDS tile: quarter (16
// lanes) per node, lane-per-edge stride 16 (round-12-verified structure),
// then each lane emits 8 bf16 features. HA is never materialized in HBM.
__global__ __launch_bounds__(256, 3) void gemm_fused_k(const float* __restrict__ x,
                                                       const int* __restrict__ row_ptr,
                                                       const int* __restrict__ esrc,
                                                       const float* __restrict__ Wrel0,
                                                       const float* __restrict__ Wroot0,
                                                       const float* __restrict__ b0,
                                                       const u16* __restrict__ WrelT,
                                                       const u16* __restrict__ WrootT,
                                                       const float* __restrict__ bias1,
                                                       u16* __restrict__ Z,
                                                       u16* __restrict__ R) {
  __shared__ u16 As[64][136];
  int tid = threadIdx.x;
  int wv = tid >> 6, lane = tid & 63;
  int m = lane & 15, quad = lane >> 4;
  int r0 = blockIdx.x * 64;

  // ---- layer 0: fill As rows (4 iterations x 4 waves x 4 quarters = 64 nodes) ----
#pragma unroll
  for (int it = 0; it < 4; ++it) {
    int nl = wv * 16 + it * 4 + quad;  // 0..63
    int node = r0 + nl;
    float a[IN_DIM];
#pragma unroll
    for (int k = 0; k < IN_DIM; ++k) a[k] = 0.f;
    if (node < N_NODES) {
      int beg = row_ptr[node], end = row_ptr[node + 1];
      for (int e = beg + m; e < end; e += 16) {
        int s = esrc[e];
#pragma unroll
        for (int k = 0; k < IN_DIM; ++k) a[k] += x[s * IN_DIM + k];
      }
    }
#pragma unroll
    for (int k = 0; k < IN_DIM; ++k) {
      a[k] += __shfl_xor(a[k], 1, 16);
      a[k] += __shfl_xor(a[k], 2, 16);
      a[k] += __shfl_xor(a[k], 4, 16);
      a[k] += __shfl_xor(a[k], 8, 16);
    }
    float xr[IN_DIM];
#pragma unroll
    for (int k = 0; k < IN_DIM; ++k) xr[k] = (node < N_NODES) ? x[node * IN_DIM + k] : 0.f;
    int c0 = m * 8;
    u16x8 w8;
#pragma unroll
    for (int j = 0; j < 8; ++j) {
      float v = (node < N_NODES) ? b0[c0 + j] : 0.f;
#pragma unroll
      for (int k = 0; k < IN_DIM; ++k) {
        v = fmaf(a[k], Wrel0[k * HID + c0 + j], v);
        v = fmaf(xr[k], Wroot0[k * HID + c0 + j], v);
      }
      w8[j] = f2bf(fmaxf(v, 0.f));
    }
    *(u16x8*)&As[nl][c0] = w8;
  }
  __syncthreads();

  // ---- layer-1 GEMM (dual: rel->Z, root+bias->R) ----
  const u16* WT = (wv < 2) ? WrelT : WrootT;
  int n0 = (wv & 1) * 64;

  f32x4 acc[4][4];
#pragma unroll
  for (int mt = 0; mt < 4; ++mt)
#pragma unroll
    for (int nt = 0; nt < 4; ++nt) acc[mt][nt] = (f32x4){0.f, 0.f, 0.f, 0.f};

#pragma unroll
  for (int ks = 0; ks < 4; ++ks) {
    int kb = ks * 32;
    bf16x8 af[4], bf[4];
#pragma unroll
    for (int mt = 0; mt < 4; ++mt)
      af[mt] = *(const bf16x8*)&As[mt * 16 + m][kb + quad * 8];
#pragma unroll
    for (int nt = 0; nt < 4; ++nt)
      bf[nt] = *(const bf16x8*)(WT + (size_t)(n0 + nt * 16 + m) * HID + kb + quad * 8);
#pragma unroll
    for (int mt = 0; mt < 4; ++mt)
#pragma unroll
      for (int nt = 0; nt < 4; ++nt)
        acc[mt][nt] = __builtin_amdgcn_mfma_f32_16x16x32_bf16(af[mt], bf[nt], acc[mt][nt], 0, 0, 0);
  }

  if (wv < 2) {
#pragma unroll
    for (int mt = 0; mt < 4; ++mt)
#pragma unroll
      for (int nt = 0; nt < 4; ++nt) {
        int col = n0 + nt * 16 + m;
#pragma unroll
        for (int r = 0; r < 4; ++r) {
          int row = r0 + mt * 16 + quad * 4 + r;
          if (row < N_NODES) Z[(size_t)row * HID + col] = f2bf(acc[mt][nt][r]);
        }
      }
  } else {
    float bl[4];
#pragma unroll
    for (int nt = 0; nt < 4; ++nt) bl[nt] = bias1[n0 + nt * 16 + m];
#pragma unroll
    for (int mt = 0; mt < 4; ++mt)
#pragma unroll
      for (int nt = 0; nt < 4; ++nt) {
        int col = n0 + nt * 16 + m;
#pragma unroll
        for (int r = 0; r < 4; ++r) {
          int row = r0 + mt * 16 + quad * 4 + r;
          if (row < N_NODES) R[(size_t)row * HID + col] = f2bf(acc[mt][nt][r] + bl[nt]);
        }
      }
  }
}

// ---- gather helper: unrolled x2, 8 edges in flight per wave ----
__device__ __forceinline__ void gather_node(const u16* __restrict__ Z,
                                            const int* __restrict__ esrc,
                                            int beg, int end, int q, int f8,
                                            f32x8& out) {
  f32x8 a0, a1;
#pragma unroll
  for (int j = 0; j < 8; ++j) { a0[j] = 0.f; a1[j] = 0.f; }
  int e = beg + q;
  for (; e + 4 < end; e += 8) {
    int s0 = esrc[e];
    int s1 = esrc[e + 4];
    u16x8 za = *(const u16x8*)(Z + (size_t)s0 * HID + f8);
    u16x8 zb = *(const u16x8*)(Z + (size_t)s1 * HID + f8);
#pragma unroll
    for (int j = 0; j < 8; ++j) { a0[j] += bf2f(za[j]); a1[j] += bf2f(zb[j]); }
  }
  if (e < end) {
    int s0 = esrc[e];
    u16x8 za = *(const u16x8*)(Z + (size_t)s0 * HID + f8);
#pragma unroll
    for (int j = 0; j < 8; ++j) a0[j] += bf2f(za[j]);
  }
#pragma unroll
  for (int j = 0; j < 8; ++j) out[j] = a0[j] + a1[j];
}

// ---------------- Layer-1 agg + layer-2 scalar collapse ----------------
// h2 = relu(R + gather(Z)) held in registers (never written);
// s_rel[n] = h2 . wvecs[0:128), s_root[n] = h2 . wvecs[128:256).
__global__ __launch_bounds__(256) void agg_s_k(const u16* __restrict__ Z,
                                               const int* __restrict__ row_ptr,
                                               const int* __restrict__ esrc,
                                               const u16* __restrict__ R,
                                               const float* __restrict__ wvecs,
                                               float* __restrict__ s_rel,
                                               float* __restrict__ s_root) {
  int wave = threadIdx.x >> 6;
  int lane = threadIdx.x & 63;
  int node = blockIdx.x * 4 + wave;
  if (node >= N_NODES) return;
  int q = lane >> 4;
  int l16 = lane & 15;
  int f8 = l16 * 8;
  int beg = row_ptr[node], end = row_ptr[node + 1];
  f32x8 acc;
  gather_node(Z, esrc, beg, end, q, f8, acc);
#pragma unroll
  for (int j = 0; j < 8; ++j) {
    acc[j] += __shfl_xor(acc[j], 16, 64);
    acc[j] += __shfl_xor(acc[j], 32, 64);
  }
  if (q == 0) {
    const u16* rp = R + (size_t)node * HID + f8;
    u16x8 r8 = *(const u16x8*)rp;
    float sr = 0.f, so = 0.f;
#pragma unroll
    for (int j = 0; j < 8; ++j) {
      float h = fmaxf(bf2f(r8[j]) + acc[j], 0.f);
      sr = fmaf(h, wvecs[f8 + j], sr);
      so = fmaf(h, wvecs[128 + f8 + j], so);
    }
#pragma unroll
    for (int w = 1; w < 16; w <<= 1) {
      sr += __shfl_xor(sr, w, 16);
      so += __shfl_xor(so, w, 16);
    }
    if (l16 == 0) {
      s_rel[node] = sr;
      s_root[node] = so;
    }
  }
}

// ---------------- Block-per-graph pooled reduction + head (NO atomics) ----------------
__global__ __launch_bounds__(256) void pool_final_k(const float* __restrict__ s_rel,
                                                    const float* __restrict__ s_root,
                                                    const int* __restrict__ esrc,
                                                    const int* __restrict__ row_ptr,
                                                    const int* __restrict__ nrow,
                                                    const float* __restrict__ wvecs,
                                                    const float* __restrict__ blin,
                                                    float* __restrict__ out) {
  int g = blockIdx.x;
  int n0 = nrow[g], n1 = nrow[g + 1];
  int e0 = row_ptr[n0], e1 = row_ptr[n1];
  float s = 0.f;
  for (int e = e0 + threadIdx.x; e < e1; e += 256) s += s_rel[esrc[e]];
  for (int n = n0 + threadIdx.x; n < n1; n += 256) s += s_root[n];
  __shared__ float red[4];
#pragma unroll
  for (int w = 32; w; w >>= 1) s += __shfl_down(s, w, 64);
  if ((threadIdx.x & 63) == 0) red[threadIdx.x >> 6] = s;
  __syncthreads();
  if (threadIdx.x == 0) {
    float t = red[0] + red[1] + red[2] + red[3];
    float cntf = (float)(n1 - n0);
    float cmax = fmaxf(cntf, 1.f);
    float logit = (t + cntf * wvecs[256]) / cmax + blin[0];
    out[g] = 1.f / (1.f + expf(-logit));
  }
}

extern "C" void kernel_launch(void* const* d_in, const int* in_sizes, int n_in,
                              void* d_out, int out_size, void* d_ws, size_t ws_size,
                              hipStream_t stream) {
  const float* x      = (const float*)d_in[0];
  const int*   ei     = (const int*)d_in[1];
  const int*   batch  = (const int*)d_in[2];
  const float* Wrel0  = (const float*)d_in[3];
  const float* brel0  = (const float*)d_in[4];
  const float* Wroot0 = (const float*)d_in[5];
  const float* Wrel1  = (const float*)d_in[6];
  const float* brel1  = (const float*)d_in[7];
  const float* Wroot1 = (const float*)d_in[8];
  const float* Wrel2  = (const float*)d_in[9];
  const float* brel2  = (const float*)d_in[10];
  const float* Wroot2 = (const float*)d_in[11];
  const float* Wlin   = (const float*)d_in[12];
  const float* blin   = (const float*)d_in[13];
  float* out = (float*)d_out;
  const int* srcp = ei;
  const int* dstp = ei + N_EDGES;

  char* ws = (char*)d_ws;
  size_t off = 0;
  auto alloc = [&](size_t b) { size_t o = off; off += (b + 255) & ~(size_t)255; return o; };
  u16*  Z     = (u16*)(ws + alloc(sizeof(u16) * N_NODES * HID));
  u16*  R     = (u16*)(ws + alloc(sizeof(u16) * N_NODES * HID));
  float* s_rel  = (float*)(ws + alloc(sizeof(float) * N_NODES));
  float* s_root = (float*)(ws + alloc(sizeof(float) * N_NODES));
  u16* WT1rel = (u16*)(ws + alloc(sizeof(u16) * HID * HID));
  u16* WT1root= (u16*)(ws + alloc(sizeof(u16) * HID * HID));
  float* wvecs = (float*)(ws + alloc(sizeof(float) * 260));
  int* row_ptr  = (int*)(ws + alloc(sizeof(int) * (N_NODES + 1)));
  int* esrc     = (int*)(ws + alloc(sizeof(int) * N_EDGES));
  int* nrow     = (int*)(ws + alloc(sizeof(int) * (NGRAPH + 1)));
  int* fill_off = (int*)(ws + alloc(sizeof(int) * N_NODES));
  size_t zero_base = off;
  int* counts   = (int*)(ws + alloc(sizeof(int) * N_NODES));
  size_t zero_len = off - zero_base;

  hipMemsetAsync(ws + zero_base, 0, zero_len, stream);

  setup_k<<<CNT_BLK + PREP_BLK + 1 + SCAN_NBLK, 256, 0, stream>>>(
      dstp, counts, Wrel1, Wroot1, WT1rel, WT1root,
      Wrel2, Wroot2, brel2, Wlin, wvecs, batch, nrow);
  scan_fused_k<<<SCAN_NBLK, 256, 0, stream>>>(counts, row_ptr, fill_off);
  fill_edges_k<<<(N_EDGES + 255) / 256, 256, 0, stream>>>(srcp, dstp, fill_off, esrc);

  // Layer 0 + layer 1 fused (gather x in input space + project + MFMA GEMM)
  gemm_fused_k<<<GEMM_NBLK, 256, 0, stream>>>(x, row_ptr, esrc, Wrel0, Wroot0, brel0,
                                              WT1rel, WT1root, brel1, Z, R);
  // Layer-1 agg fused with layer-2 scalar collapse
  agg_s_k<<<(N_NODES + 3) / 4, 256, 0, stream>>>(Z, row_ptr, esrc, R, wvecs, s_rel, s_root);
  // Block-per-graph pooled reduction + sigmoid head (no atomics)
  pool_final_k<<<NGRAPH, 256, 0, stream>>>(s_rel, s_root, esrc, row_ptr, nrow, wvecs, blin, out);
}

// Round 18
// 238.371 us; speedup vs baseline: 1.2123x; 1.2123x over previous
//
#include <hip/hip_runtime.h>
#include <hip/hip_bf16.h>
#include <math.h>

#define N_NODES 50000
#define N_EDGES 640000
#define IN_DIM 5
#define HID 128
#define NGRAPH 512
#define SCAN_NBLK ((N_NODES + 255) / 256)  // 196
#define GEMM_NBLK ((N_NODES + 63) / 64)    // 782
#define CNT_BLK ((N_EDGES + 255) / 256)    // 2500
#define PREP_BLK 128                        // 2 weight mats x 64

typedef unsigned short u16;
typedef __attribute__((ext_vector_type(8))) short bf16x8;
typedef __attribute__((ext_vector_type(8))) unsigned short u16x8;
typedef __attribute__((ext_vector_type(4))) float f32x4;
typedef __attribute__((ext_vector_type(8))) float f32x8;

__device__ __forceinline__ float bf2f(u16 u) {
  union { unsigned int i; float f; } v; v.i = ((unsigned int)u) << 16; return v.f;
}
__device__ __forceinline__ u16 f2bf(float f) {
  return __bfloat16_as_ushort(__float2bfloat16(f));
}

// ---------------- Fused setup: count_edges + W1 prep + wvecs + nrow ----------------
// wvecs[0:128) = Wrel2@Wlin, [128:256) = Wroot2@Wlin, [256] = b2.Wlin
__global__ __launch_bounds__(256) void setup_k(const int* __restrict__ dst,
                                               int* __restrict__ counts,
                                               const float* __restrict__ W1rel,
                                               const float* __restrict__ W1root,
                                               u16* __restrict__ T1rel, u16* __restrict__ T1root,
                                               const float* __restrict__ Wrel2,
                                               const float* __restrict__ Wroot2,
                                               const float* __restrict__ b2,
                                               const float* __restrict__ Wlin,
                                               float* __restrict__ wvecs,
                                               const int* __restrict__ batch,
                                               int* __restrict__ nrow) {
  int b = blockIdx.x;
  if (b < CNT_BLK) {
    int e = b * 256 + threadIdx.x;
    if (e < N_EDGES) atomicAdd(&counts[dst[e]], 1);
  } else if (b < CNT_BLK + PREP_BLK) {
    int bb = b - CNT_BLK;
    int which = bb >> 6;
    int idx = (bb & 63) * 256 + threadIdx.x;  // k*128 + n
    const float* W = which == 0 ? W1rel : W1root;
    u16* T = which == 0 ? T1rel : T1root;
    int k = idx >> 7, n = idx & 127;
    T[n * HID + k] = f2bf(W[idx]);
  } else if (b == CNT_BLK + PREP_BLK) {
    int t = threadIdx.x;
    if (t < 128) {
      float s = 0.f;
      for (int c = 0; c < HID; ++c) s = fmaf(Wrel2[t * HID + c], Wlin[c], s);
      wvecs[t] = s;
    } else {
      int k = t - 128;
      float s = 0.f;
      for (int c = 0; c < HID; ++c) s = fmaf(Wroot2[k * HID + c], Wlin[c], s);
      wvecs[128 + k] = s;
    }
    if (t == 0) {
      float s = 0.f;
      for (int c = 0; c < HID; ++c) s = fmaf(b2[c], Wlin[c], s);
      wvecs[256] = s;
    }
  } else {
    // nrow: graph node boundaries from sorted batch (handles empty graphs)
    int n = (b - CNT_BLK - PREP_BLK - 1) * 256 + threadIdx.x;
    if (n < N_NODES) {
      int bg = batch[n];
      int bp = (n == 0) ? -1 : batch[n - 1];
      for (int g = bp + 1; g <= bg; ++g) nrow[g] = n;
      if (n == N_NODES - 1) {
        for (int g = bg + 1; g <= NGRAPH; ++g) nrow[g] = N_NODES;
      }
    }
  }
}

__global__ __launch_bounds__(256) void partial_k(const int* __restrict__ counts,
                                                 int* __restrict__ bsum) {
  int t = threadIdx.x;
  int i = blockIdx.x * 256 + t;
  int v = (i < N_NODES) ? counts[i] : 0;
#pragma unroll
  for (int off = 32; off; off >>= 1) v += __shfl_down(v, off, 64);
  __shared__ int ws[4];
  if ((t & 63) == 0) ws[t >> 6] = v;
  __syncthreads();
  if (t == 0) bsum[blockIdx.x] = ws[0] + ws[1] + ws[2] + ws[3];
}

// write_scan2: local scan + self-computed block offset
__global__ __launch_bounds__(256) void write_scan2_k(const int* __restrict__ counts,
                                                     const int* __restrict__ bsum,
                                                     int* __restrict__ row_ptr,
                                                     int* __restrict__ fill_off) {
  __shared__ int s[256];
  __shared__ int wred[4];
  int t = threadIdx.x;
  int b = blockIdx.x;
  int v = (t < b) ? bsum[t] : 0;
#pragma unroll
  for (int off = 32; off; off >>= 1) v += __shfl_down(v, off, 64);
  if ((t & 63) == 0) wred[t >> 6] = v;
  __syncthreads();
  int boff = wred[0] + wred[1] + wred[2] + wred[3];
  if (b == SCAN_NBLK - 1 && t == 0) {
    row_ptr[N_NODES] = boff + bsum[b];
  }
  __syncthreads();
  int i = b * 256 + t;
  int c = (i < N_NODES) ? counts[i] : 0;
  s[t] = c;
  __syncthreads();
#pragma unroll
  for (int off = 1; off < 256; off <<= 1) {
    int u = (t >= off) ? s[t - off] : 0;
    __syncthreads();
    s[t] += u;
    __syncthreads();
  }
  int excl = s[t] - c + boff;
  if (i < N_NODES) {
    row_ptr[i] = excl;
    fill_off[i] = excl;
  }
}

__global__ void fill_edges_k(const int* __restrict__ src, const int* __restrict__ dst,
                             int* __restrict__ fill_off, int* __restrict__ esrc) {
  int e = blockIdx.x * blockDim.x + threadIdx.x;
  if (e < N_EDGES) {
    int d = dst[e];
    int pos = atomicAdd(&fill_off[d], 1);
    esrc[pos] = src[e];
  }
}

// ---------------- Fused layer 0: gather x (input space) + project, wave per node ----
// (r17 lesson: do NOT fuse this gather into the GEMM block — serializing a
// latency-bound gather behind MFMA at 21% occupancy cost 3x. Keep it a fat
// independent-wave kernel.)
__global__ __launch_bounds__(256) void proj0_fused_k(const float* __restrict__ x,
                                                     const int* __restrict__ row_ptr,
                                                     const int* __restrict__ esrc,
                                                     const float* __restrict__ Wrel,
                                                     const float* __restrict__ Wroot,
                                                     const float* __restrict__ bias,
                                                     u16* __restrict__ HA) {
  int wave = threadIdx.x >> 6;
  int lane = threadIdx.x & 63;
  int node = blockIdx.x * 4 + wave;
  if (node >= N_NODES) return;
  int beg = row_ptr[node], end = row_ptr[node + 1];
  float a[IN_DIM];
#pragma unroll
  for (int k = 0; k < IN_DIM; ++k) a[k] = 0.f;
  for (int e = beg + lane; e < end; e += 64) {
    int s = esrc[e];
#pragma unroll
    for (int k = 0; k < IN_DIM; ++k) a[k] += x[s * IN_DIM + k];
  }
#pragma unroll
  for (int k = 0; k < IN_DIM; ++k) {
#pragma unroll
    for (int w = 1; w < 64; w <<= 1) a[k] += __shfl_xor(a[k], w, 64);
  }
  float xr[IN_DIM];
#pragma unroll
  for (int k = 0; k < IN_DIM; ++k) xr[k] = x[node * IN_DIM + k];
  int c0 = lane * 2;
  float v0 = bias[c0], v1 = bias[c0 + 1];
#pragma unroll
  for (int k = 0; k < IN_DIM; ++k) {
    v0 = fmaf(a[k], Wrel[k * HID + c0], v0);
    v0 = fmaf(xr[k], Wroot[k * HID + c0], v0);
    v1 = fmaf(a[k], Wrel[k * HID + c0 + 1], v1);
    v1 = fmaf(xr[k], Wroot[k * HID + c0 + 1], v1);
  }
  ushort2 w2;
  w2.x = f2bf(fmaxf(v0, 0.f));
  w2.y = f2bf(fmaxf(v1, 0.f));
  *(ushort2*)(HA + (size_t)node * HID + c0) = w2;
}

// ---------------- MFMA GEMM layer 1 (dual: rel->Z, root+bias->R, both bf16) ----------
__global__ __launch_bounds__(256, 3) void gemm_mfma_k(const u16* __restrict__ A,
                                                      const u16* __restrict__ WrelT,
                                                      const u16* __restrict__ WrootT,
                                                      const float* __restrict__ bias,
                                                      u16* __restrict__ Z,
                                                      u16* __restrict__ R) {
  __shared__ u16 As[64][136];
  int tid = threadIdx.x;
  int wv = tid >> 6, lane = tid & 63;
  int m = lane & 15, quad = lane >> 4;
  int r0 = blockIdx.x * 64;

#pragma unroll
  for (int it = 0; it < 4; ++it) {
    int idx = it * 256 + tid;
    int row = idx >> 4, q = idx & 15;
    int grow = r0 + row;
    float4 v = make_float4(0.f, 0.f, 0.f, 0.f);
    if (grow < N_NODES) v = *(const float4*)(A + (size_t)grow * HID + q * 8);
    *(float4*)&As[row][q * 8] = v;
  }
  __syncthreads();

  const u16* WT = (wv < 2) ? WrelT : WrootT;
  int n0 = (wv & 1) * 64;

  f32x4 acc[4][4];
#pragma unroll
  for (int mt = 0; mt < 4; ++mt)
#pragma unroll
    for (int nt = 0; nt < 4; ++nt) acc[mt][nt] = (f32x4){0.f, 0.f, 0.f, 0.f};

#pragma unroll
  for (int ks = 0; ks < 4; ++ks) {
    int kb = ks * 32;
    bf16x8 af[4], bf[4];
#pragma unroll
    for (int mt = 0; mt < 4; ++mt)
      af[mt] = *(const bf16x8*)&As[mt * 16 + m][kb + quad * 8];
#pragma unroll
    for (int nt = 0; nt < 4; ++nt)
      bf[nt] = *(const bf16x8*)(WT + (size_t)(n0 + nt * 16 + m) * HID + kb + quad * 8);
#pragma unroll
    for (int mt = 0; mt < 4; ++mt)
#pragma unroll
      for (int nt = 0; nt < 4; ++nt)
        acc[mt][nt] = __builtin_amdgcn_mfma_f32_16x16x32_bf16(af[mt], bf[nt], acc[mt][nt], 0, 0, 0);
  }

  if (wv < 2) {
#pragma unroll
    for (int mt = 0; mt < 4; ++mt)
#pragma unroll
      for (int nt = 0; nt < 4; ++nt) {
        int col = n0 + nt * 16 + m;
#pragma unroll
        for (int r = 0; r < 4; ++r) {
          int row = r0 + mt * 16 + quad * 4 + r;
          if (row < N_NODES) Z[(size_t)row * HID + col] = f2bf(acc[mt][nt][r]);
        }
      }
  } else {
    float bl[4];
#pragma unroll
    for (int nt = 0; nt < 4; ++nt) bl[nt] = bias[n0 + nt * 16 + m];
#pragma unroll
    for (int mt = 0; mt < 4; ++mt)
#pragma unroll
      for (int nt = 0; nt < 4; ++nt) {
        int col = n0 + nt * 16 + m;
#pragma unroll
        for (int r = 0; r < 4; ++r) {
          int row = r0 + mt * 16 + quad * 4 + r;
          if (row < N_NODES) R[(size_t)row * HID + col] = f2bf(acc[mt][nt][r] + bl[nt]);
        }
      }
  }
}

// ---- gather helper: unrolled x2, 8 edges in flight per wave ----
__device__ __forceinline__ void gather_node(const u16* __restrict__ Z,
                                            const int* __restrict__ esrc,
                                            int beg, int end, int q, int f8,
                                            f32x8& out) {
  f32x8 a0, a1;
#pragma unroll
  for (int j = 0; j < 8; ++j) { a0[j] = 0.f; a1[j] = 0.f; }
  int e = beg + q;
  for (; e + 4 < end; e += 8) {
    int s0 = esrc[e];
    int s1 = esrc[e + 4];
    u16x8 za = *(const u16x8*)(Z + (size_t)s0 * HID + f8);
    u16x8 zb = *(const u16x8*)(Z + (size_t)s1 * HID + f8);
#pragma unroll
    for (int j = 0; j < 8; ++j) { a0[j] += bf2f(za[j]); a1[j] += bf2f(zb[j]); }
  }
  if (e < end) {
    int s0 = esrc[e];
    u16x8 za = *(const u16x8*)(Z + (size_t)s0 * HID + f8);
#pragma unroll
    for (int j = 0; j < 8; ++j) a0[j] += bf2f(za[j]);
  }
#pragma unroll
  for (int j = 0; j < 8; ++j) out[j] = a0[j] + a1[j];
}

// ---------------- Layer-1 agg + layer-2 scalar collapse ----------------
// h2 = relu(R + gather(Z)) held in registers (never written);
// s_rel[n] = h2 . wvecs[0:128), s_root[n] = h2 . wvecs[128:256).
__global__ __launch_bounds__(256) void agg_s_k(const u16* __restrict__ Z,
                                               const int* __restrict__ row_ptr,
                                               const int* __restrict__ esrc,
                                               const u16* __restrict__ R,
                                               const float* __restrict__ wvecs,
                                               float* __restrict__ s_rel,
                                               float* __restrict__ s_root) {
  int wave = threadIdx.x >> 6;
  int lane = threadIdx.x & 63;
  int node = blockIdx.x * 4 + wave;
  if (node >= N_NODES) return;
  int q = lane >> 4;
  int l16 = lane & 15;
  int f8 = l16 * 8;
  int beg = row_ptr[node], end = row_ptr[node + 1];
  f32x8 acc;
  gather_node(Z, esrc, beg, end, q, f8, acc);
#pragma unroll
  for (int j = 0; j < 8; ++j) {
    acc[j] += __shfl_xor(acc[j], 16, 64);
    acc[j] += __shfl_xor(acc[j], 32, 64);
  }
  if (q == 0) {
    const u16* rp = R + (size_t)node * HID + f8;
    u16x8 r8 = *(const u16x8*)rp;
    float sr = 0.f, so = 0.f;
#pragma unroll
    for (int j = 0; j < 8; ++j) {
      float h = fmaxf(bf2f(r8[j]) + acc[j], 0.f);
      sr = fmaf(h, wvecs[f8 + j], sr);
      so = fmaf(h, wvecs[128 + f8 + j], so);
    }
#pragma unroll
    for (int w = 1; w < 16; w <<= 1) {
      sr += __shfl_xor(sr, w, 16);
      so += __shfl_xor(so, w, 16);
    }
    if (l16 == 0) {
      s_rel[node] = sr;
      s_root[node] = so;
    }
  }
}

// ---------------- Block-per-graph pooled reduction + head (NO atomics) ----------------
__global__ __launch_bounds__(256) void pool_final_k(const float* __restrict__ s_rel,
                                                    const float* __restrict__ s_root,
                                                    const int* __restrict__ esrc,
                                                    const int* __restrict__ row_ptr,
                                                    const int* __restrict__ nrow,
                                                    const float* __restrict__ wvecs,
                                                    const float* __restrict__ blin,
                                                    float* __restrict__ out) {
  int g = blockIdx.x;
  int n0 = nrow[g], n1 = nrow[g + 1];
  int e0 = row_ptr[n0], e1 = row_ptr[n1];
  float s = 0.f;
  for (int e = e0 + threadIdx.x; e < e1; e += 256) s += s_rel[esrc[e]];
  for (int n = n0 + threadIdx.x; n < n1; n += 256) s += s_root[n];
  __shared__ float red[4];
#pragma unroll
  for (int w = 32; w; w >>= 1) s += __shfl_down(s, w, 64);
  if ((threadIdx.x & 63) == 0) red[threadIdx.x >> 6] = s;
  __syncthreads();
  if (threadIdx.x == 0) {
    float t = red[0] + red[1] + red[2] + red[3];
    float cntf = (float)(n1 - n0);
    float cmax = fmaxf(cntf, 1.f);
    float logit = (t + cntf * wvecs[256]) / cmax + blin[0];
    out[g] = 1.f / (1.f + expf(-logit));
  }
}

extern "C" void kernel_launch(void* const* d_in, const int* in_sizes, int n_in,
                              void* d_out, int out_size, void* d_ws, size_t ws_size,
                              hipStream_t stream) {
  const float* x      = (const float*)d_in[0];
  const int*   ei     = (const int*)d_in[1];
  const int*   batch  = (const int*)d_in[2];
  const float* Wrel0  = (const float*)d_in[3];
  const float* brel0  = (const float*)d_in[4];
  const float* Wroot0 = (const float*)d_in[5];
  const float* Wrel1  = (const float*)d_in[6];
  const float* brel1  = (const float*)d_in[7];
  const float* Wroot1 = (const float*)d_in[8];
  const float* Wrel2  = (const float*)d_in[9];
  const float* brel2  = (const float*)d_in[10];
  const float* Wroot2 = (const float*)d_in[11];
  const float* Wlin   = (const float*)d_in[12];
  const float* blin   = (const float*)d_in[13];
  float* out = (float*)d_out;
  const int* srcp = ei;
  const int* dstp = ei + N_EDGES;

  char* ws = (char*)d_ws;
  size_t off = 0;
  auto alloc = [&](size_t b) { size_t o = off; off += (b + 255) & ~(size_t)255; return o; };
  u16*  Z     = (u16*)(ws + alloc(sizeof(u16) * N_NODES * HID));
  u16*  HA    = (u16*)(ws + alloc(sizeof(u16) * N_NODES * HID));
  u16*  R     = (u16*)(ws + alloc(sizeof(u16) * N_NODES * HID));
  float* s_rel  = (float*)(ws + alloc(sizeof(float) * N_NODES));
  float* s_root = (float*)(ws + alloc(sizeof(float) * N_NODES));
  u16* WT1rel = (u16*)(ws + alloc(sizeof(u16) * HID * HID));
  u16* WT1root= (u16*)(ws + alloc(sizeof(u16) * HID * HID));
  float* wvecs = (float*)(ws + alloc(sizeof(float) * 260));
  int* row_ptr  = (int*)(ws + alloc(sizeof(int) * (N_NODES + 1)));
  int* esrc     = (int*)(ws + alloc(sizeof(int) * N_EDGES));
  int* nrow     = (int*)(ws + alloc(sizeof(int) * (NGRAPH + 1)));
  int* fill_off = (int*)(ws + alloc(sizeof(int) * N_NODES));
  int* bsum     = (int*)(ws + alloc(sizeof(int) * 256));
  size_t zero_base = off;
  int* counts   = (int*)(ws + alloc(sizeof(int) * N_NODES));
  size_t zero_len = off - zero_base;

  hipMemsetAsync(ws + zero_base, 0, zero_len, stream);

  setup_k<<<CNT_BLK + PREP_BLK + 1 + SCAN_NBLK, 256, 0, stream>>>(
      dstp, counts, Wrel1, Wroot1, WT1rel, WT1root,
      Wrel2, Wroot2, brel2, Wlin, wvecs, batch, nrow);
  partial_k<<<SCAN_NBLK, 256, 0, stream>>>(counts, bsum);
  write_scan2_k<<<SCAN_NBLK, 256, 0, stream>>>(counts, bsum, row_ptr, fill_off);
  fill_edges_k<<<(N_EDGES + 255) / 256, 256, 0, stream>>>(srcp, dstp, fill_off, esrc);

  // Layer 0 fused (gather x in input space + project)
  proj0_fused_k<<<(N_NODES + 3) / 4, 256, 0, stream>>>(x, row_ptr, esrc, Wrel0, Wroot0, brel0, HA);
  // Layer 1 GEMM (rel->Z, root+bias->R)
  gemm_mfma_k<<<GEMM_NBLK, 256, 0, stream>>>(HA, WT1rel, WT1root, brel1, Z, R);
  // Layer-1 agg fused with layer-2 scalar collapse
  agg_s_k<<<(N_NODES + 3) / 4, 256, 0, stream>>>(Z, row_ptr, esrc, R, wvecs, s_rel, s_root);
  // Block-per-graph pooled reduction + sigmoid head (no atomics)
  pool_final_k<<<NGRAPH, 256, 0, stream>>>(s_rel, s_root, esrc, row_ptr, nrow, wvecs, blin, out);
}